// Round 1
// baseline (304.121 us; speedup 1.0000x reference)
//
#include <hip/hip_runtime.h>

// Grad3D: out = |dx| + |dy| + |dz| with central differences, zero padding.
// Input/output: fp32, shape (4, 1, 192, 224, 192), contiguous.

constexpr int W  = 192;
constexpr int H  = 224;
constexpr int D  = 192;
constexpr int B  = 4;
constexpr int W4     = W / 4;        // 48 float4 per row
constexpr int PLANE4 = W4 * H;       // 10752 float4 per z-plane
constexpr int VOL4   = PLANE4 * D;   // float4 per batch volume
constexpr int TOTAL4 = VOL4 * B;     // 8,257,536 float4 total

__global__ __launch_bounds__(256) void grad3d_kernel(
    const float* __restrict__ in, float* __restrict__ out) {
    int idx = blockIdx.x * 256 + threadIdx.x;
    if (idx >= TOTAL4) return;

    // Decompose: idx = ((b*D + z)*H + y)*W4 + xv
    int xv = idx % W4;
    int t  = idx / W4;
    int y  = t % H;
    t      = t / H;          // global plane index (b*D + z)
    int z  = t % D;

    const float4* in4 = (const float4*)in;
    const float4 zero = make_float4(0.f, 0.f, 0.f, 0.f);

    float4 c  = in4[idx];
    float4 zp = (z + 1 < D) ? in4[idx + PLANE4] : zero;   // z+1 plane
    float4 zm = (z > 0)     ? in4[idx - PLANE4] : zero;   // z-1 plane
    float4 yp = (y + 1 < H) ? in4[idx + W4]     : zero;   // y+1 row
    float4 ym = (y > 0)     ? in4[idx - W4]     : zero;   // y-1 row
    float left  = (xv > 0)      ? in[idx * 4 - 1] : 0.f;  // x-1 of lane 0
    float right = (xv + 1 < W4) ? in[idx * 4 + 4] : 0.f;  // x+1 of lane 3

    float4 r;
    r.x = fabsf((c.y  - left)*0.5f) + fabsf((yp.x - ym.x)*0.5f) + fabsf((zp.x - zm.x)*0.5f);
    r.y = fabsf((c.z  - c.x )*0.5f) + fabsf((yp.y - ym.y)*0.5f) + fabsf((zp.y - zm.y)*0.5f);
    r.z = fabsf((c.w  - c.y )*0.5f) + fabsf((yp.z - ym.z)*0.5f) + fabsf((zp.z - zm.z)*0.5f);
    r.w = fabsf((right - c.z)*0.5f) + fabsf((yp.w - ym.w)*0.5f) + fabsf((zp.w - zm.w)*0.5f);

    ((float4*)out)[idx] = r;
}

extern "C" void kernel_launch(void* const* d_in, const int* in_sizes, int n_in,
                              void* d_out, int out_size, void* d_ws, size_t ws_size,
                              hipStream_t stream) {
    const float* x = (const float*)d_in[0];
    float* out     = (float*)d_out;
    int blocks = (TOTAL4 + 255) / 256;
    grad3d_kernel<<<blocks, 256, 0, stream>>>(x, out);
}

// Round 2
// 251.809 us; speedup vs baseline: 1.2077x; 1.2077x over previous
//
#include <hip/hip_runtime.h>

// Grad3D: out = |dx| + |dy| + |dz|, central differences, zero padding.
// fp32, shape (4, 1, 192, 224, 192), contiguous.
//
// z-march version: each thread owns a 4-wide (float4) x-segment and walks
// CHUNK z-planes. z-neighbors (cm/c0/cp) live in rolling registers, so the
// z+-1 plane global reads of the naive kernel (and their cross-XCD L2
// duplication) are eliminated. Loads for plane z+1 are issued before the
// compute of plane z -> one full iteration of latency hiding.

constexpr int W = 192, H = 224, D = 192, B = 4;
constexpr int W4     = W / 4;       // 48 float4 per row
constexpr int PLANE4 = W4 * H;      // 10752 float4 per plane
constexpr int CHUNK  = 16;          // z planes per thread
constexpr int ZC     = D / CHUNK;   // 12 z-chunks
constexpr int BY     = 8;           // rows per block
constexpr int YT     = H / BY;      // 28 y-tiles

__global__ __launch_bounds__(384) void grad3d_kernel(
    const float* __restrict__ in, float* __restrict__ out) {
    const int xv = threadIdx.x;     // 0..47  (float4 index within row)
    const int ty = threadIdx.y;     // 0..7
    int bb = blockIdx.x;
    const int yt = bb % YT; bb /= YT;
    const int zc = bb % ZC; bb /= ZC;
    const int b  = bb;
    const int y  = yt * BY + ty;
    const int z0 = zc * CHUNK;
    const int x0 = xv * 4;

    const float4* __restrict__ in4 = (const float4*)in;
    float4* __restrict__ out4 = (float4*)out;
    const float4 zero4 = make_float4(0.f, 0.f, 0.f, 0.f);

    const bool has_yp = (y + 1 < H);
    const bool has_ym = (y > 0);
    const bool has_l  = (x0 > 0);
    const bool has_r  = (x0 + 4 < W);

    // float4 index of this thread's center element at plane z0
    int base = (b * D + z0) * PLANE4 + y * W4 + xv;

    // ---- preload state for output plane z0 ----
    float4 cm = (z0 > 0) ? in4[base - PLANE4] : zero4;   // c(z0-1)
    float4 c0 = in4[base];                               // c(z0)
    float4 cp = in4[base + PLANE4];                      // c(z0+1), always in range (z0<=176)
    float4 yp0 = has_yp ? in4[base + W4] : zero4;
    float4 ym0 = has_ym ? in4[base - W4] : zero4;
    float  l0  = has_l  ? in[base * 4 - 1] : 0.f;
    float  r0  = has_r  ? in[base * 4 + 4] : 0.f;

#pragma unroll
    for (int i = 0; i < CHUNK; ++i) {
        const int z = z0 + i;
        const int nbase = base + PLANE4;          // plane z+1
        const bool vz1 = (z + 1 < D);             // rows at z+1 exist
        const bool vz2 = (z + 2 < D);             // center at z+2 exists

        // ---- prefetch for output plane z+1 ----
        float4 cn  = vz2 ? in4[nbase + PLANE4] : zero4;   // c(z+2)
        float4 ypn = (vz1 && has_yp) ? in4[nbase + W4] : zero4;
        float4 ymn = (vz1 && has_ym) ? in4[nbase - W4] : zero4;
        float  ln  = (vz1 && has_l)  ? in[nbase * 4 - 1] : 0.f;
        float  rn  = (vz1 && has_r)  ? in[nbase * 4 + 4] : 0.f;

        // ---- compute output plane z from registers ----
        float4 r;
        r.x = fabsf((c0.y - l0  ) * 0.5f) + fabsf((yp0.x - ym0.x) * 0.5f)
            + fabsf((cp.x - cm.x) * 0.5f);
        r.y = fabsf((c0.z - c0.x) * 0.5f) + fabsf((yp0.y - ym0.y) * 0.5f)
            + fabsf((cp.y - cm.y) * 0.5f);
        r.z = fabsf((c0.w - c0.y) * 0.5f) + fabsf((yp0.z - ym0.z) * 0.5f)
            + fabsf((cp.z - cm.z) * 0.5f);
        r.w = fabsf((r0   - c0.z) * 0.5f) + fabsf((yp0.w - ym0.w) * 0.5f)
            + fabsf((cp.w - cm.w) * 0.5f);
        out4[base] = r;

        // ---- roll state ----
        cm = c0; c0 = cp; cp = cn;
        yp0 = ypn; ym0 = ymn; l0 = ln; r0 = rn;
        base = nbase;
    }
}

extern "C" void kernel_launch(void* const* d_in, const int* in_sizes, int n_in,
                              void* d_out, int out_size, void* d_ws, size_t ws_size,
                              hipStream_t stream) {
    const float* x = (const float*)d_in[0];
    float* out     = (float*)d_out;
    dim3 block(W4, BY);                     // (48, 8) = 384 threads = 6 waves
    dim3 grid(B * ZC * YT);                 // 4*12*28 = 1344 blocks
    grad3d_kernel<<<grid, block, 0, stream>>>(x, out);
}

// Round 3
// 248.982 us; speedup vs baseline: 1.2215x; 1.0114x over previous
//
#include <hip/hip_runtime.h>

// Grad3D: out = |dx|+|dy|+|dz|, central differences, zero padding.
// fp32, (4,1,192,224,192) contiguous.
//
// R3: z-march + 2-adjacent-rows-per-thread (y-neighbors mostly in-register),
// CHUNK=8 for a 2688-block grid (10.5 blocks/CU), XCD-contiguous swizzle.

constexpr int W = 192, H = 224, D = 192, B = 4;
constexpr int W4     = W / 4;        // 48 float4 per row
constexpr int PLANE4 = W4 * H;       // 10752
constexpr int BYP    = 4;            // row-pairs per block (threadIdx.y)
constexpr int ROWS   = BYP * 2;      // 8 rows per block
constexpr int CHUNK  = 8;            // z planes per thread
constexpr int ZC     = D / CHUNK;    // 24
constexpr int YT     = H / ROWS;     // 28
constexpr int GRID   = B * ZC * YT;  // 2688
constexpr int PERX   = GRID / 8;     // 336 blocks per XCD

__global__ __launch_bounds__(192) void grad3d_kernel(
    const float* __restrict__ in, float* __restrict__ out) {
    // XCD-contiguous swizzle: HW sends bid round-robin to XCDs (bid%8);
    // remap so each XCD owns a contiguous spatial slab of 336 blocks.
    int bid = blockIdx.x;
    int sid = (bid & 7) * PERX + (bid >> 3);
    const int yt = sid % YT; sid /= YT;
    const int zc = sid % ZC; sid /= ZC;
    const int b  = sid;

    const int xv = threadIdx.x;          // 0..47 (float4 within row)
    const int tp = threadIdx.y;          // 0..3  (row pair)
    const int r0 = yt * ROWS + tp * 2;   // even row of the pair
    const int r1 = r0 + 1;
    const int z0 = zc * CHUNK;

    const float4* __restrict__ in4 = (const float4*)in;
    float4* __restrict__ out4 = (float4*)out;
    const float4 zf = make_float4(0.f, 0.f, 0.f, 0.f);

    const bool has_l  = (xv > 0);
    const bool has_r  = (xv < W4 - 1);
    const bool has_ym = (r0 > 0);        // row r0-1 exists
    const bool has_yp = (r1 + 1 < H);    // row r1+1 exists

    // float4 index of (b, z0, r0, xv)
    int base = (b * D + z0) * PLANE4 + r0 * W4 + xv;

    // Rolling state for output plane z: centers of rows r0,r1 at z-1,z,z+1;
    // y-neighbor rows (r0-1, r1+1) at z; x-edge scalars at z.
    float4 cm0 = (z0 > 0) ? in4[base - PLANE4]      : zf;
    float4 cm1 = (z0 > 0) ? in4[base - PLANE4 + W4] : zf;
    float4 c00 = in4[base];
    float4 c01 = in4[base + W4];
    float4 cp0 = in4[base + PLANE4];          // z0+1 <= 185, in range
    float4 cp1 = in4[base + PLANE4 + W4];
    float4 ym  = has_ym ? in4[base - W4]     : zf;   // row r0-1
    float4 yp  = has_yp ? in4[base + 2 * W4] : zf;   // row r1+1
    float  l0  = has_l ? in[base * 4 - 1]        : 0.f;
    float  r0e = has_r ? in[base * 4 + 4]        : 0.f;
    float  l1  = has_l ? in[(base + W4) * 4 - 1] : 0.f;
    float  r1e = has_r ? in[(base + W4) * 4 + 4] : 0.f;

#pragma unroll
    for (int i = 0; i < CHUNK; ++i) {
        const int z  = z0 + i;
        const int nb = base + PLANE4;
        const bool vz1 = (z + 1 < D);
        const bool vz2 = (z + 2 < D);

        // ---- prefetch state for output plane z+1 ----
        float4 cn0 = vz2 ? in4[nb + PLANE4]      : zf;
        float4 cn1 = vz2 ? in4[nb + PLANE4 + W4] : zf;
        float4 ymn = (vz1 && has_ym) ? in4[nb - W4]     : zf;
        float4 ypn = (vz1 && has_yp) ? in4[nb + 2 * W4] : zf;
        float  l0n = (vz1 && has_l) ? in[nb * 4 - 1]        : 0.f;
        float  r0n = (vz1 && has_r) ? in[nb * 4 + 4]        : 0.f;
        float  l1n = (vz1 && has_l) ? in[(nb + W4) * 4 - 1] : 0.f;
        float  r1n = (vz1 && has_r) ? in[(nb + W4) * 4 + 4] : 0.f;

        // ---- compute plane z: row r0 (y-: ym, y+: c01), row r1 (y-: c00, y+: yp)
        float4 o0, o1;
        o0.x = fabsf((c00.y - l0   ) * .5f) + fabsf((c01.x - ym.x) * .5f) + fabsf((cp0.x - cm0.x) * .5f);
        o0.y = fabsf((c00.z - c00.x) * .5f) + fabsf((c01.y - ym.y) * .5f) + fabsf((cp0.y - cm0.y) * .5f);
        o0.z = fabsf((c00.w - c00.y) * .5f) + fabsf((c01.z - ym.z) * .5f) + fabsf((cp0.z - cm0.z) * .5f);
        o0.w = fabsf((r0e  - c00.z) * .5f) + fabsf((c01.w - ym.w) * .5f) + fabsf((cp0.w - cm0.w) * .5f);
        o1.x = fabsf((c01.y - l1   ) * .5f) + fabsf((yp.x - c00.x) * .5f) + fabsf((cp1.x - cm1.x) * .5f);
        o1.y = fabsf((c01.z - c01.x) * .5f) + fabsf((yp.y - c00.y) * .5f) + fabsf((cp1.y - cm1.y) * .5f);
        o1.z = fabsf((c01.w - c01.y) * .5f) + fabsf((yp.z - c00.z) * .5f) + fabsf((cp1.z - cm1.z) * .5f);
        o1.w = fabsf((r1e  - c01.z) * .5f) + fabsf((yp.w - c00.w) * .5f) + fabsf((cp1.w - cm1.w) * .5f);
        out4[base]      = o0;
        out4[base + W4] = o1;

        // ---- roll ----
        cm0 = c00; cm1 = c01; c00 = cp0; c01 = cp1; cp0 = cn0; cp1 = cn1;
        ym = ymn; yp = ypn; l0 = l0n; r0e = r0n; l1 = l1n; r1e = r1n;
        base = nb;
    }
}

extern "C" void kernel_launch(void* const* d_in, const int* in_sizes, int n_in,
                              void* d_out, int out_size, void* d_ws, size_t ws_size,
                              hipStream_t stream) {
    const float* x = (const float*)d_in[0];
    float* out     = (float*)d_out;
    dim3 block(W4, BYP);                 // (48,4) = 192 threads = 3 waves
    grad3d_kernel<<<GRID, block, 0, stream>>>(x, out);
}